// Round 1
// baseline (510.280 us; speedup 1.0000x reference)
//
#include <hip/hip_runtime.h>

typedef unsigned short USH;
typedef float v2f __attribute__((ext_vector_type(2)));

__device__ __forceinline__ float bf2f(USH u) {
    return __uint_as_float(((unsigned int)u) << 16);
}
__device__ __forceinline__ USH f2bf(float f) {
    unsigned int i = __float_as_uint(f);
    i += 0x7FFFu + ((i >> 16) & 1u);   // RNE; values are finite
    return (USH)(i >> 16);
}
__device__ __forceinline__ v2f relu2(v2f s) {
    return __builtin_elementwise_max(s, (v2f)(0.0f));
}

// flag: 1 = global inputs are bf16, 0 = f32
__device__ __forceinline__ float ldf(const void* p, long idx, int bf) {
    return bf ? bf2f(((const USH*)p)[idx]) : ((const float*)p)[idx];
}
__device__ __forceinline__ void ld4(const void* p, long idx, int bf, float o[4]) {
    if (bf) {
        ushort4 u = *(const ushort4*)((const USH*)p + idx);
        o[0] = bf2f(u.x); o[1] = bf2f(u.y); o[2] = bf2f(u.z); o[3] = bf2f(u.w);
    } else {
        float4 v = *(const float4*)((const float*)p + idx);
        o[0] = v.x; o[1] = v.y; o[2] = v.z; o[3] = v.w;
    }
}

// dtype detect from Ind (U(0,1) values). bf16: every ushort < 0x8000.
__device__ __forceinline__ int detect_bf(const void* ind) {
    const uint4* p = (const uint4*)ind;
    unsigned o = 0;
    #pragma unroll
    for (int i = 0; i < 8; ++i) { uint4 v = p[i]; o |= v.x | v.y | v.z | v.w; }
    return (o & 0x8000u) == 0;
}

// NOTE (R7/R8 post-mortem, prior session): a t-split k_amkt with grid (16,16,8)
// writing per-t partials showed 76x HBM read amplification — that structure is
// banned. This round keeps the single fused k_main but restructures it to a
// wave-row decomposition (lane = m, 8 n-rows per wave):
//   - A-side (hA rows) is wave-UNIFORM -> scalar-pipe loads (s_load), consumed
//     as the SGPR-pair operand of v_pk_add_f32. Off the LDS and VALU pipes.
//   - B-side is the only LDS traffic: 32 ds_read_b64 per wave per t (16x less
//     than the old 2x2-microtile scheme), conflict-free.
// Workspace layouts (all f32, written by k_pre_d):
//   hAf [9][1024 n][64 c]      (tile 8 = W1s/section-B tile)
//   hBf [9][32 cp][1024 m][2]  (c-paired so lane's c-pair = one ds_read_b64)

// ---------------------------------------------------------------------------
// Kernel 1 (merged): blocks [0,2048) compute D[k][n][m] = E_k E_k^T (bf16);
// blocks [2048,2336) compute the h-buffers (f32, new layouts).
// ---------------------------------------------------------------------------
__global__ __launch_bounds__(256) void k_pre_d(
    const void* __restrict__ x,    // [1024][8][64]
    const void* __restrict__ W1m,  // [128][64]
    const void* __restrict__ b1m,  // [64]
    const void* __restrict__ W1s,  // [128][64]
    const void* __restrict__ b1s,  // [64]
    const void* __restrict__ E,    // [8][1024][64]
    const void* __restrict__ IndDet,
    float* __restrict__ hAf,       // [9][1024][64] f32
    float* __restrict__ hBf,       // [9][32][1024][2] f32
    USH* __restrict__ D)           // [8][1024][1024] bf16
{
    __shared__ float smem[8192];
    float* sA = smem;          // 4096
    float* sB = smem + 4096;   // 4096
    const int bf = detect_bf(IndDet);
    const int tid = threadIdx.x;
    const int bid = blockIdx.x;
    const int tx = tid & 15, ty = tid >> 4;

    if (bid < 2048) {
        // ---- D part (unchanged, proven) ----
        const int mb = (bid & 15) * 64, nb = ((bid >> 4) & 15) * 64, k = bid >> 8;
        const long ek = (long)k * 65536;
        {
            const int r_l = tid >> 2, cq = tid & 3;
            const long bn = ek + (long)(nb + r_l) * 64 + cq * 16;
            const long bm = ek + (long)(mb + r_l) * 64 + cq * 16;
            #pragma unroll
            for (int j = 0; j < 4; ++j) {
                const int c0 = cq * 16 + j * 4;
                float o[4];
                ld4(E, bn + j * 4, bf, o);
                #pragma unroll
                for (int e = 0; e < 4; ++e) sA[(c0 + e) * 64 + r_l] = o[e];
                ld4(E, bm + j * 4, bf, o);
                #pragma unroll
                for (int e = 0; e < 4; ++e) sB[(c0 + e) * 64 + r_l] = o[e];
            }
        }
        __syncthreads();
        const int m0 = tx * 4, n0 = ty * 4;
        v2f acc2[4][2] = {};  // [ni][m pair-half], packed along m
        #pragma unroll 8
        for (int c = 0; c < 64; ++c) {
            const float4 an = *(const float4*)&sA[c * 64 + n0];
            const float4 am = *(const float4*)&sB[c * 64 + m0];
            const float aa[4] = {an.x, an.y, an.z, an.w};
            v2f m01; m01.x = am.x; m01.y = am.y;
            v2f m23; m23.x = am.z; m23.y = am.w;
            #pragma unroll
            for (int ni = 0; ni < 4; ++ni) {
                const v2f av = (v2f)(aa[ni]);
                acc2[ni][0] = __builtin_elementwise_fma(av, m01, acc2[ni][0]);
                acc2[ni][1] = __builtin_elementwise_fma(av, m23, acc2[ni][1]);
            }
        }
        #pragma unroll
        for (int ni = 0; ni < 4; ++ni) {
            ushort4 o;
            o.x = f2bf(acc2[ni][0].x); o.y = f2bf(acc2[ni][0].y);
            o.z = f2bf(acc2[ni][1].x); o.w = f2bf(acc2[ni][1].y);
            *(ushort4*)&D[(long)k * 1048576 + (long)(nb + n0 + ni) * 1024 + mb + m0] = o;
        }
    } else {
        // ---- precompute part: h = x_t @ W1 (+bias on B-side), f32 out ----
        const int bid2 = bid - 2048;
        const int nbase = (bid2 & 15) * 64;
        const int by = bid2 >> 4;   // 0..17
        int t, rb;
        const void* Wsrc;
        const void* bias;
        float* dst;
        if (by < 8)        { t = by;     rb = 0;  Wsrc = W1m; bias = nullptr; dst = hAf + by * 65536; }
        else if (by < 16)  { t = by - 8; rb = 64; Wsrc = W1m; bias = b1m;     dst = hBf + (by - 8) * 65536; }
        else if (by == 16) { t = 7;      rb = 0;  Wsrc = W1s; bias = nullptr; dst = hAf + 8 * 65536; }
        else               { t = 7;      rb = 64; Wsrc = W1s; bias = b1s;     dst = hBf + 8 * 65536; }

        {   // stage x tile -> sA[d][n] (transpose on LDS write)
            const int n_l = tid >> 2, dq = tid & 3;
            const long base = (long)(nbase + n_l) * 512 + t * 64 + dq * 16;
            #pragma unroll
            for (int j = 0; j < 4; ++j) {
                float o[4]; ld4(x, base + j * 4, bf, o);
                const int d0 = dq * 16 + j * 4;
                #pragma unroll
                for (int e = 0; e < 4; ++e) sA[(d0 + e) * 64 + n_l] = o[e];
            }
        }
        {   // stage W tile -> sB[d][c]
            const int d_l = tid >> 2, cq = tid & 3;
            const long base = (long)(rb + d_l) * 64 + cq * 16;
            #pragma unroll
            for (int j = 0; j < 4; ++j) {
                float o[4]; ld4(Wsrc, base + j * 4, bf, o);
                const int c0 = cq * 16 + j * 4;
                #pragma unroll
                for (int e = 0; e < 4; ++e) sB[d_l * 64 + c0 + e] = o[e];
            }
        }
        __syncthreads();

        const int c0 = tx * 4, nq = ty * 4;
        float acc[4][4] = {};  // [ci][ni]
        #pragma unroll 16
        for (int d = 0; d < 64; ++d) {
            const float4 xa = *(const float4*)&sA[d * 64 + nq];
            const float4 wv = *(const float4*)&sB[d * 64 + c0];
            const float aa[4] = {xa.x, xa.y, xa.z, xa.w};
            const float ww[4] = {wv.x, wv.y, wv.z, wv.w};
            #pragma unroll
            for (int ci = 0; ci < 4; ++ci)
                #pragma unroll
                for (int ni = 0; ni < 4; ++ni)
                    acc[ci][ni] += ww[ci] * aa[ni];
        }
        if (rb == 0) {
            // A-side: n-major rows for scalar loads: dst[n][c]
            #pragma unroll
            for (int ni = 0; ni < 4; ++ni) {
                float4 o;
                o.x = acc[0][ni]; o.y = acc[1][ni]; o.z = acc[2][ni]; o.w = acc[3][ni];
                *(float4*)&dst[(nbase + nq + ni) * 64 + c0] = o;
            }
        } else {
            // B-side: c-paired [cp][m][2], bias folded in
            float b[4];
            #pragma unroll
            for (int ci = 0; ci < 4; ++ci) b[ci] = ldf(bias, c0 + ci, bf);
            #pragma unroll
            for (int ni = 0; ni < 4; ++ni) {
                const int mr = nbase + nq + ni;
                v2f o0; o0.x = acc[0][ni] + b[0]; o0.y = acc[1][ni] + b[1];
                v2f o1; o1.x = acc[2][ni] + b[2]; o1.y = acc[3][ni] + b[3];
                *(v2f*)&dst[(c0 >> 1) * 2048 + mr * 2] = o0;
                *(v2f*)&dst[((c0 >> 1) + 1) * 2048 + mr * 2] = o1;
            }
        }
    }
}

// ---------------------------------------------------------------------------
// Kernel 2: fused pairwise kernel, wave-row decomposition.
// Block = 256 thr = 4 waves; wave covers 8 n-rows x 64 m-cols (lane = m).
// Grid (16 m-tiles, 32 n-tiles) = 512 blocks = 2 blocks/CU.
// A-side: uniform f32 rows (scalar loads). B-side: LDS, double-buffered.
// ---------------------------------------------------------------------------
__global__ __launch_bounds__(256, 2) void k_main(
    const float* __restrict__ hAf,  // [9][1024][64]
    const float* __restrict__ hBf,  // [9][32][1024][2]
    const USH* __restrict__ Dm,     // [8][1024][1024] bf16
    const void* __restrict__ Ind, const void* __restrict__ Loc,
    const void* __restrict__ a, const void* __restrict__ W2m,
    const void* __restrict__ b2m, const void* __restrict__ W2s,
    const void* __restrict__ b2s, const void* __restrict__ g,
    void* __restrict__ out)
{
    __shared__ float Bs[2][4096];   // [32 cp][64 m][2] f32, 16 KB each
    __shared__ float w2s_l[512];    // [c][k]

    const int bf = detect_bf(Ind);
    const int tid = threadIdx.x;
    const int mb = blockIdx.x * 64;
    const int nb = blockIdx.y * 32;
    const int lane = tid & 63;
    const int wid = __builtin_amdgcn_readfirstlane(tid >> 6);  // uniform wave id
    const int m = mb + lane;
    const int scp = tid >> 5;           // staging: cp sub-row 0..7
    const int sq4 = (tid & 31) << 2;    // staging: float4 offset in row

    // stage tile 0 (reg -> LDS)
    #pragma unroll
    for (int i = 0; i < 4; ++i) {
        const int cp = i * 8 + scp;
        const float4 v = *(const float4*)(hBf + cp * 2048 + mb * 2 + sq4);
        *(float4*)&Bs[0][cp * 128 + sq4] = v;
    }
    // w2s -> LDS [c][k] (straight copy of W2s [64][8])
    if (tid < 128) {
        float o[4];
        ld4(W2s, tid * 4, bf, o);
        w2s_l[tid * 4 + 0] = o[0]; w2s_l[tid * 4 + 1] = o[1];
        w2s_l[tid * 4 + 2] = o[2]; w2s_l[tid * 4 + 3] = o[3];
    }

    // uniform weights in regs (broadcast loads, once)
    v2f w2mv[32];
    #pragma unroll
    for (int q = 0; q < 16; ++q) {
        float o[4]; ld4(W2m, q * 4, bf, o);
        v2f u; u.x = o[0]; u.y = o[1]; w2mv[2 * q] = u;
        v2f w; w.x = o[2]; w.y = o[3]; w2mv[2 * q + 1] = w;
    }
    const float b2m_f = ldf(b2m, 0, bf);
    float asf[8];
    {
        float av[8], mx = -1e30f, s = 0.0f;
        #pragma unroll
        for (int k = 0; k < 8; ++k) { av[k] = ldf(a, k, bf); mx = fmaxf(mx, av[k]); }
        #pragma unroll
        for (int k = 0; k < 8; ++k) { av[k] = __expf(av[k] - mx); s += av[k]; }
        #pragma unroll
        for (int k = 0; k < 8; ++k) asf[k] = av[k] / s;
    }
    __syncthreads();

    float amk[8] = {0.f, 0.f, 0.f, 0.f, 0.f, 0.f, 0.f, 0.f};

    // ---- Section A: A_mkt over 8 time steps (double-buffered B tiles) ----
    for (int t = 0; t < 8; ++t) {
        const int cur = t & 1;
        // prefetch next tile (t+1; t==7 stages tile 8 = section-B tile)
        float4 st[4];
        #pragma unroll
        for (int i = 0; i < 4; ++i) {
            const int cp = i * 8 + scp;
            st[i] = *(const float4*)(hBf + (t + 1) * 65536 + cp * 2048 + mb * 2 + sq4);
        }

        v2f acc[8];
        #pragma unroll
        for (int ni = 0; ni < 8; ++ni) acc[ni] = (v2f)(0.0f);
        const float* At = hAf + ((t * 1024) + nb + wid * 8) * 64;  // uniform base
        #pragma unroll
        for (int ch = 0; ch < 4; ++ch) {
            v2f bbv[8];
            #pragma unroll
            for (int j = 0; j < 8; ++j)
                bbv[j] = *(const v2f*)&Bs[cur][(ch * 8 + j) * 128 + lane * 2];
            #pragma unroll
            for (int ni = 0; ni < 8; ++ni) {
                const v2f* Ar = (const v2f*)(At + ni * 64 + ch * 16);  // uniform
                #pragma unroll
                for (int j = 0; j < 8; ++j) {
                    const v2f s = relu2(bbv[j] + Ar[j]);
                    acc[ni] = __builtin_elementwise_fma(s, w2mv[ch * 8 + j], acc[ni]);
                }
            }
        }
        const float as_t = asf[t];
        #pragma unroll
        for (int ni = 0; ni < 8; ++ni)
            amk[ni] += fmaxf(acc[ni].x + acc[ni].y + b2m_f, 0.0f) * as_t;

        // write staged tile, then barrier
        #pragma unroll
        for (int i = 0; i < 4; ++i) {
            const int cp = i * 8 + scp;
            *(float4*)&Bs[cur ^ 1][cp * 128 + sq4] = st[i];
        }
        __syncthreads();
    }

    // ---- Section B: logits from tile 8 (now in Bs[0]) ----
    v2f lg[8][4];   // [ni][k-pair]
    #pragma unroll
    for (int ni = 0; ni < 8; ++ni)
        #pragma unroll
        for (int kp = 0; kp < 4; ++kp) lg[ni][kp] = (v2f)(0.0f);

    const float* A8 = hAf + (8 * 1024 + nb + wid * 8) * 64;  // uniform base
    #pragma unroll
    for (int ch = 0; ch < 16; ++ch) {   // 2 cp (4 c) per chunk
        const v2f bb0 = *(const v2f*)&Bs[0][(ch * 2 + 0) * 128 + lane * 2];
        const v2f bb1 = *(const v2f*)&Bs[0][(ch * 2 + 1) * 128 + lane * 2];
        v2f wsl[4][4];  // [c in chunk][k-pair], uniform
        #pragma unroll
        for (int cc = 0; cc < 4; ++cc) {
            const float4 wa = *(const float4*)&w2s_l[(ch * 4 + cc) * 8];
            const float4 wb = *(const float4*)&w2s_l[(ch * 4 + cc) * 8 + 4];
            wsl[cc][0].x = wa.x; wsl[cc][0].y = wa.y;
            wsl[cc][1].x = wa.z; wsl[cc][1].y = wa.w;
            wsl[cc][2].x = wb.x; wsl[cc][2].y = wb.y;
            wsl[cc][3].x = wb.z; wsl[cc][3].y = wb.w;
        }
        #pragma unroll
        for (int ni = 0; ni < 8; ++ni) {
            const v2f* Ar = (const v2f*)(A8 + ni * 64 + ch * 4);  // uniform
            const v2f s0 = relu2(bb0 + Ar[0]);
            const v2f s1 = relu2(bb1 + Ar[1]);
            #pragma unroll
            for (int kp = 0; kp < 4; ++kp) {
                lg[ni][kp] = __builtin_elementwise_fma((v2f)(s0.x), wsl[0][kp], lg[ni][kp]);
                lg[ni][kp] = __builtin_elementwise_fma((v2f)(s0.y), wsl[1][kp], lg[ni][kp]);
                lg[ni][kp] = __builtin_elementwise_fma((v2f)(s1.x), wsl[2][kp], lg[ni][kp]);
                lg[ni][kp] = __builtin_elementwise_fma((v2f)(s1.y), wsl[3][kp], lg[ni][kp]);
            }
        }
    }

    // ---- Epilogue: softmax(relu(lg+b2s)+g) . D  (no max-sub: values small) ----
    v2f b2sv[4];
    #pragma unroll
    for (int kp = 0; kp < 4; ++kp) {
        b2sv[kp].x = ldf(b2s, 2 * kp, bf);
        b2sv[kp].y = ldf(b2s, 2 * kp + 1, bf);
    }

    #pragma unroll
    for (int ni = 0; ni < 8; ++ni) {
        const int n = nb + wid * 8 + ni;
        const long rowoff = ((long)n << 10) + m;
        float gv[8];
        ld4(g, rowoff * 8, bf, gv);
        ld4(g, rowoff * 8 + 4, bf, gv + 4);
        float ssum = 0.0f, dsum = 0.0f;
        #pragma unroll
        for (int kp = 0; kp < 4; ++kp) {
            const v2f lr = relu2(lg[ni][kp] + b2sv[kp]);
            const float e0 = __expf(lr.x + gv[2 * kp]);
            const float e1 = __expf(lr.y + gv[2 * kp + 1]);
            ssum += e0 + e1;
            dsum += bf2f(Dm[((long)(2 * kp) << 20) + rowoff]) * e0
                  + bf2f(Dm[((long)(2 * kp + 1) << 20) + rowoff]) * e1;
        }
        const float nobs = dsum / ssum;
        if (bf) {
            USH* o = (USH*)out;
            o[rowoff] = ((const USH*)Ind)[rowoff];
            o[1048576 + rowoff] = ((const USH*)Loc)[rowoff];
            o[2 * 1048576 + rowoff] = f2bf(amk[ni]);
            o[3 * 1048576 + rowoff] = f2bf(nobs);
        } else {
            float* o = (float*)out;
            o[rowoff] = ((const float*)Ind)[rowoff];
            o[1048576 + rowoff] = ((const float*)Loc)[rowoff];
            o[2 * 1048576 + rowoff] = amk[ni];
            o[3 * 1048576 + rowoff] = nobs;
        }
    }
}

extern "C" void kernel_launch(void* const* d_in, const int* in_sizes, int n_in,
                              void* d_out, int out_size, void* d_ws, size_t ws_size,
                              hipStream_t stream) {
    const void* x   = d_in[0];
    const void* Ind = d_in[1];
    const void* Loc = d_in[2];
    const void* a   = d_in[3];
    const void* W1m = d_in[4];
    const void* b1m = d_in[5];
    const void* W2m = d_in[6];
    const void* b2m = d_in[7];
    const void* W1s = d_in[8];
    const void* b1s = d_in[9];
    const void* W2s = d_in[10];
    const void* b2s = d_in[11];
    const void* E   = d_in[12];
    const void* g   = d_in[13];

    float* ws  = (float*)d_ws;
    float* hAf = ws;                    // [9][1024][64] f32, 2.25 MB
    float* hBf = hAf + 589824;          // [9][32][1024][2] f32, 2.25 MB
    USH*   Dm  = (USH*)(hBf + 589824);  // [8][1024][1024] bf16, 16 MB

    k_pre_d<<<dim3(2336), 256, 0, stream>>>(x, W1m, b1m, W1s, b1s, E, Ind,
                                            hAf, hBf, Dm);
    k_main<<<dim3(16, 32), 256, 0, stream>>>(hAf, hBf, Dm,
                                             Ind, Loc, a, W2m, b2m, W2s, b2s,
                                             g, d_out);
}

// Round 2
// 193.892 us; speedup vs baseline: 2.6318x; 2.6318x over previous
//
#include <hip/hip_runtime.h>

typedef unsigned short USH;
typedef float v2f __attribute__((ext_vector_type(2)));

__device__ __forceinline__ float bf2f(USH u) {
    return __uint_as_float(((unsigned int)u) << 16);
}
__device__ __forceinline__ USH f2bf(float f) {
    unsigned int i = __float_as_uint(f);
    i += 0x7FFFu + ((i >> 16) & 1u);   // RNE; values are finite
    return (USH)(i >> 16);
}
__device__ __forceinline__ v2f relu2(v2f s) {
    return __builtin_elementwise_max(s, (v2f)(0.0f));
}

// flag: 1 = global inputs are bf16, 0 = f32
__device__ __forceinline__ float ldf(const void* p, long idx, int bf) {
    return bf ? bf2f(((const USH*)p)[idx]) : ((const float*)p)[idx];
}
__device__ __forceinline__ void ld4(const void* p, long idx, int bf, float o[4]) {
    if (bf) {
        ushort4 u = *(const ushort4*)((const USH*)p + idx);
        o[0] = bf2f(u.x); o[1] = bf2f(u.y); o[2] = bf2f(u.z); o[3] = bf2f(u.w);
    } else {
        float4 v = *(const float4*)((const float*)p + idx);
        o[0] = v.x; o[1] = v.y; o[2] = v.z; o[3] = v.w;
    }
}

// dtype detect from Ind (U(0,1) values). bf16: every ushort < 0x8000.
__device__ __forceinline__ int detect_bf(const void* ind) {
    const uint4* p = (const uint4*)ind;
    unsigned o = 0;
    #pragma unroll
    for (int i = 0; i < 8; ++i) { uint4 v = p[i]; o |= v.x | v.y | v.z | v.w; }
    return (o & 0x8000u) == 0;
}

// NOTE (R7/R8 post-mortem, prior session): per-t global partial writes showed
// 76x HBM read amplification — banned. NOTE (R1 this session): wave-uniform
// GLOBAL loads as inner-loop operands serialize on waitcnt at low occupancy
// (VALUBusy 9%, 6x regression) — inner-loop operands must come from LDS.
// Workspace layouts (f32, written by k_pre_d):
//   hAf [9][64 c][1024 n]   (tile 8 = W1s/section-B tile)
//   hBf [9][64 c][1024 m]   (bias b1m/b1s folded in)

// ---------------------------------------------------------------------------
// Kernel 1 (merged): blocks [0,2048) compute D[k][n][m] = E_k E_k^T (bf16);
// blocks [2048,2336) compute the h-buffers (f32, [c][row] layout).
// ---------------------------------------------------------------------------
__global__ __launch_bounds__(256) void k_pre_d(
    const void* __restrict__ x,    // [1024][8][64]
    const void* __restrict__ W1m,  // [128][64]
    const void* __restrict__ b1m,  // [64]
    const void* __restrict__ W1s,  // [128][64]
    const void* __restrict__ b1s,  // [64]
    const void* __restrict__ E,    // [8][1024][64]
    const void* __restrict__ IndDet,
    float* __restrict__ hAf,       // [9][64][1024] f32
    float* __restrict__ hBf,       // [9][64][1024] f32
    USH* __restrict__ D)           // [8][1024][1024] bf16
{
    __shared__ float smem[8192];
    float* sA = smem;          // 4096
    float* sB = smem + 4096;   // 4096
    const int bf = detect_bf(IndDet);
    const int tid = threadIdx.x;
    const int bid = blockIdx.x;
    const int tx = tid & 15, ty = tid >> 4;

    if (bid < 2048) {
        // ---- D part (unchanged, proven) ----
        const int mb = (bid & 15) * 64, nb = ((bid >> 4) & 15) * 64, k = bid >> 8;
        const long ek = (long)k * 65536;
        {
            const int r_l = tid >> 2, cq = tid & 3;
            const long bn = ek + (long)(nb + r_l) * 64 + cq * 16;
            const long bm = ek + (long)(mb + r_l) * 64 + cq * 16;
            #pragma unroll
            for (int j = 0; j < 4; ++j) {
                const int c0 = cq * 16 + j * 4;
                float o[4];
                ld4(E, bn + j * 4, bf, o);
                #pragma unroll
                for (int e = 0; e < 4; ++e) sA[(c0 + e) * 64 + r_l] = o[e];
                ld4(E, bm + j * 4, bf, o);
                #pragma unroll
                for (int e = 0; e < 4; ++e) sB[(c0 + e) * 64 + r_l] = o[e];
            }
        }
        __syncthreads();
        const int m0 = tx * 4, n0 = ty * 4;
        v2f acc2[4][2] = {};  // [ni][m pair-half], packed along m
        #pragma unroll 8
        for (int c = 0; c < 64; ++c) {
            const float4 an = *(const float4*)&sA[c * 64 + n0];
            const float4 am = *(const float4*)&sB[c * 64 + m0];
            const float aa[4] = {an.x, an.y, an.z, an.w};
            v2f m01; m01.x = am.x; m01.y = am.y;
            v2f m23; m23.x = am.z; m23.y = am.w;
            #pragma unroll
            for (int ni = 0; ni < 4; ++ni) {
                const v2f av = (v2f)(aa[ni]);
                acc2[ni][0] = __builtin_elementwise_fma(av, m01, acc2[ni][0]);
                acc2[ni][1] = __builtin_elementwise_fma(av, m23, acc2[ni][1]);
            }
        }
        #pragma unroll
        for (int ni = 0; ni < 4; ++ni) {
            ushort4 o;
            o.x = f2bf(acc2[ni][0].x); o.y = f2bf(acc2[ni][0].y);
            o.z = f2bf(acc2[ni][1].x); o.w = f2bf(acc2[ni][1].y);
            *(ushort4*)&D[(long)k * 1048576 + (long)(nb + n0 + ni) * 1024 + mb + m0] = o;
        }
    } else {
        // ---- precompute part: h = x_t @ W1 (+bias on B-side), f32 out ----
        const int bid2 = bid - 2048;
        const int nbase = (bid2 & 15) * 64;
        const int by = bid2 >> 4;   // 0..17
        int t, rb;
        const void* Wsrc;
        const void* bias;
        float* dst;
        if (by < 8)        { t = by;     rb = 0;  Wsrc = W1m; bias = nullptr; dst = hAf + by * 65536; }
        else if (by < 16)  { t = by - 8; rb = 64; Wsrc = W1m; bias = b1m;     dst = hBf + (by - 8) * 65536; }
        else if (by == 16) { t = 7;      rb = 0;  Wsrc = W1s; bias = nullptr; dst = hAf + 8 * 65536; }
        else               { t = 7;      rb = 64; Wsrc = W1s; bias = b1s;     dst = hBf + 8 * 65536; }

        {   // stage x tile -> sA[d][n] (transpose on LDS write)
            const int n_l = tid >> 2, dq = tid & 3;
            const long base = (long)(nbase + n_l) * 512 + t * 64 + dq * 16;
            #pragma unroll
            for (int j = 0; j < 4; ++j) {
                float o[4]; ld4(x, base + j * 4, bf, o);
                const int d0 = dq * 16 + j * 4;
                #pragma unroll
                for (int e = 0; e < 4; ++e) sA[(d0 + e) * 64 + n_l] = o[e];
            }
        }
        {   // stage W tile -> sB[d][c]
            const int d_l = tid >> 2, cq = tid & 3;
            const long base = (long)(rb + d_l) * 64 + cq * 16;
            #pragma unroll
            for (int j = 0; j < 4; ++j) {
                float o[4]; ld4(Wsrc, base + j * 4, bf, o);
                const int c0 = cq * 16 + j * 4;
                #pragma unroll
                for (int e = 0; e < 4; ++e) sB[d_l * 64 + c0 + e] = o[e];
            }
        }
        __syncthreads();

        const int c0 = tx * 4, nq = ty * 4;
        float acc[4][4] = {};  // [ci][ni]
        #pragma unroll 16
        for (int d = 0; d < 64; ++d) {
            const float4 xa = *(const float4*)&sA[d * 64 + nq];
            const float4 wv = *(const float4*)&sB[d * 64 + c0];
            const float aa[4] = {xa.x, xa.y, xa.z, xa.w};
            const float ww[4] = {wv.x, wv.y, wv.z, wv.w};
            #pragma unroll
            for (int ci = 0; ci < 4; ++ci)
                #pragma unroll
                for (int ni = 0; ni < 4; ++ni)
                    acc[ci][ni] += ww[ci] * aa[ni];
        }
        // write [c][row] f32; bias folded on B-side
        float b[4] = {0.f, 0.f, 0.f, 0.f};
        if (bias) {
            #pragma unroll
            for (int ci = 0; ci < 4; ++ci) b[ci] = ldf(bias, c0 + ci, bf);
        }
        #pragma unroll
        for (int ci = 0; ci < 4; ++ci) {
            float4 o;
            o.x = acc[ci][0] + b[ci]; o.y = acc[ci][1] + b[ci];
            o.z = acc[ci][2] + b[ci]; o.w = acc[ci][3] + b[ci];
            *(float4*)&dst[(c0 + ci) * 1024 + nbase + nq] = o;
        }
    }
}

// ---------------------------------------------------------------------------
// Kernel 2: fused pairwise kernel. Block tile 64n x 32m, 256 threads,
// per-thread 4n x 2m (m packed in v2f). Grid (32 m-tiles, 16 n-tiles) = 512
// blocks = 2 blocks/CU. f32 LDS tiles, double-buffered across t.
// ---------------------------------------------------------------------------
__global__ __launch_bounds__(256, 2) void k_main(
    const float* __restrict__ hAf,  // [9][64][1024]
    const float* __restrict__ hBf,  // [9][64][1024]
    const USH* __restrict__ Dm,     // [8][1024][1024] bf16
    const void* __restrict__ Ind, const void* __restrict__ Loc,
    const void* __restrict__ a, const void* __restrict__ W2m,
    const void* __restrict__ b2m, const void* __restrict__ W2s,
    const void* __restrict__ b2s, const void* __restrict__ g,
    void* __restrict__ out)
{
    __shared__ float As[2][4096];   // [64 c][64 n] f32, 16 KB each
    __shared__ float Bs[2][2048];   // [64 c][32 m] f32, 8 KB each
    __shared__ float w2s_l[512];    // [c][k]
    __shared__ float w2m_l[64];
    __shared__ float asoft_l[8];

    const int bf = detect_bf(Ind);
    const int tid = threadIdx.x;
    const int mb = blockIdx.x * 32, nb = blockIdx.y * 64;
    const int tx = tid & 15, ty = tid >> 4;
    const int n0 = ty * 4;          // local n of this thread's 4 rows
    const int m0 = tx * 2;          // local m of this thread's 2 cols

    // staging thread->chunk maps (float4 chunks)
    const int cA = tid >> 4, qA = (tid & 15) * 4;   // A: 16 chunks/row, 4 rows/pass
    const int cB = tid >> 3, qB = (tid & 7) * 4;    // B: 8 chunks/row, 2 passes

    // -- weight staging --
    if (tid < 64) w2m_l[tid] = ldf(W2m, tid, bf);
    if (tid >= 64 && tid < 192) {
        const int q = tid - 64;  // 0..127
        float o[4]; ld4(W2s, q * 4, bf, o);
        #pragma unroll
        for (int e = 0; e < 4; ++e) w2s_l[q * 4 + e] = o[e];
    }
    if (tid < 8) {
        float av[8], mx = -1e30f, s = 0.0f;
        #pragma unroll
        for (int k = 0; k < 8; ++k) { av[k] = ldf(a, k, bf); mx = fmaxf(mx, av[k]); }
        #pragma unroll
        for (int k = 0; k < 8; ++k) s += __expf(av[k] - mx);
        asoft_l[tid] = __expf(av[tid] - mx) / s;
    }
    const float b2m_f = ldf(b2m, 0, bf);

    // -- initial stage: t=0 into buffer 0 (straight f32 copies) --
    #pragma unroll
    for (int p = 0; p < 4; ++p) {
        const int c = cA + p * 16;
        *(float4*)&As[0][c * 64 + qA] = *(const float4*)(hAf + (long)c * 1024 + nb + qA);
    }
    #pragma unroll
    for (int p = 0; p < 2; ++p) {
        const int c = cB + p * 32;
        *(float4*)&Bs[0][c * 32 + qB] = *(const float4*)(hBf + (long)c * 1024 + mb + qB);
    }
    __syncthreads();

    v2f amk[4] = {(v2f)(0.0f), (v2f)(0.0f), (v2f)(0.0f), (v2f)(0.0f)};

    // ---- Section A: A_mkt over 8 time steps (double-buffered) ----
    for (int t = 0; t < 8; ++t) {
        const int cur = t & 1, nxt = cur ^ 1;
        // prefetch tile t+1 to regs (t=7 stages tile 8 = section-B tile)
        const float* srcA = hAf + (long)(t + 1) * 65536;
        const float* srcB = hBf + (long)(t + 1) * 65536;
        float4 pfa[4], pfb[2];
        #pragma unroll
        for (int p = 0; p < 4; ++p)
            pfa[p] = *(const float4*)(srcA + (long)(cA + p * 16) * 1024 + nb + qA);
        #pragma unroll
        for (int p = 0; p < 2; ++p)
            pfb[p] = *(const float4*)(srcB + (long)(cB + p * 32) * 1024 + mb + qB);

        v2f acc[4] = {(v2f)(0.0f), (v2f)(0.0f), (v2f)(0.0f), (v2f)(0.0f)};
        const float* Ac = As[cur];
        const float* Bc = Bs[cur];
        #pragma unroll 4
        for (int c4 = 0; c4 < 16; ++c4) {
            const float4 wq = *(const float4*)&w2m_l[c4 * 4];
            const float ww[4] = {wq.x, wq.y, wq.z, wq.w};
            #pragma unroll
            for (int j = 0; j < 4; ++j) {
                const int c = c4 * 4 + j;
                const float4 aq = *(const float4*)&Ac[c * 64 + n0];
                const v2f bb = *(const v2f*)&Bc[c * 32 + m0];
                const float aa[4] = {aq.x, aq.y, aq.z, aq.w};
                const v2f wv = (v2f)(ww[j]);
                #pragma unroll
                for (int ni = 0; ni < 4; ++ni) {
                    const v2f s = relu2(bb + (v2f)(aa[ni]));
                    acc[ni] = __builtin_elementwise_fma(s, wv, acc[ni]);
                }
            }
        }
        const v2f asv = (v2f)(asoft_l[t]);
        const v2f b2v = (v2f)(b2m_f);
        #pragma unroll
        for (int ni = 0; ni < 4; ++ni)
            amk[ni] = __builtin_elementwise_fma(relu2(acc[ni] + b2v), asv, amk[ni]);

        // write staged tile to the other buffer, then barrier
        #pragma unroll
        for (int p = 0; p < 4; ++p)
            *(float4*)&As[nxt][(cA + p * 16) * 64 + qA] = pfa[p];
        #pragma unroll
        for (int p = 0; p < 2; ++p)
            *(float4*)&Bs[nxt][(cB + p * 32) * 32 + qB] = pfb[p];
        __syncthreads();
    }

    // ---- Section B: logits (tile 8 in buffer 0 from t=7 prefetch) ----
    v2f lgm[4][8];  // [ni][k], packed along m
    #pragma unroll
    for (int ni = 0; ni < 4; ++ni)
        #pragma unroll
        for (int k = 0; k < 8; ++k) lgm[ni][k] = (v2f)(0.0f);

    #pragma unroll 2
    for (int c4 = 0; c4 < 16; ++c4) {
        #pragma unroll
        for (int j = 0; j < 4; ++j) {
            const int c = c4 * 4 + j;
            const float4 aq = *(const float4*)&As[0][c * 64 + n0];
            const v2f bb = *(const v2f*)&Bs[0][c * 32 + m0];
            const float aa[4] = {aq.x, aq.y, aq.z, aq.w};
            const float4 wa = *(const float4*)&w2s_l[c * 8];
            const float4 wb = *(const float4*)&w2s_l[c * 8 + 4];
            const float wk[8] = {wa.x, wa.y, wa.z, wa.w, wb.x, wb.y, wb.z, wb.w};
            #pragma unroll
            for (int ni = 0; ni < 4; ++ni) {
                const v2f z = relu2(bb + (v2f)(aa[ni]));
                #pragma unroll
                for (int k = 0; k < 8; ++k)
                    lgm[ni][k] = __builtin_elementwise_fma(z, (v2f)(wk[k]), lgm[ni][k]);
            }
        }
    }

    // ---- Epilogue: softmax(relu(lg+b2s)+g) . D  (no max-sub: values small) ----
    float b2sv[8];
    #pragma unroll
    for (int k = 0; k < 8; ++k) b2sv[k] = ldf(b2s, k, bf);

    const int mg = mb + m0;
    #pragma unroll
    for (int ni = 0; ni < 4; ++ni) {
        const int n = nb + n0 + ni;
        const long rowoff = ((long)n << 10) + mg;
        float gv[16];
        ld4(g, rowoff * 8 + 0, bf, gv + 0);
        ld4(g, rowoff * 8 + 4, bf, gv + 4);
        ld4(g, rowoff * 8 + 8, bf, gv + 8);
        ld4(g, rowoff * 8 + 12, bf, gv + 12);

        float s0 = 0.0f, s1 = 0.0f, d0 = 0.0f, d1 = 0.0f;
        #pragma unroll
        for (int k = 0; k < 8; ++k) {
            const v2f lr = relu2(lgm[ni][k] + (v2f)(b2sv[k]));
            const float e0 = __expf(lr.x + gv[k]);
            const float e1 = __expf(lr.y + gv[8 + k]);
            s0 += e0; s1 += e1;
            const ushort2 dv = *(const ushort2*)&Dm[((long)k << 20) + rowoff];
            d0 += bf2f(dv.x) * e0;
            d1 += bf2f(dv.y) * e1;
        }

        if (bf) {
            USH* o = (USH*)out;
            *(ushort2*)&o[rowoff] = *(const ushort2*)&((const USH*)Ind)[rowoff];
            *(ushort2*)&o[1048576 + rowoff] = *(const ushort2*)&((const USH*)Loc)[rowoff];
            ushort2 o2; o2.x = f2bf(amk[ni].x); o2.y = f2bf(amk[ni].y);
            *(ushort2*)&o[2 * 1048576 + rowoff] = o2;
            ushort2 o3; o3.x = f2bf(d0 / s0); o3.y = f2bf(d1 / s1);
            *(ushort2*)&o[3 * 1048576 + rowoff] = o3;
        } else {
            float* o = (float*)out;
            *(float2*)&o[rowoff] = *(const float2*)&((const float*)Ind)[rowoff];
            *(float2*)&o[1048576 + rowoff] = *(const float2*)&((const float*)Loc)[rowoff];
            float2 o2; o2.x = amk[ni].x; o2.y = amk[ni].y;
            *(float2*)&o[2 * 1048576 + rowoff] = o2;
            float2 o3; o3.x = d0 / s0; o3.y = d1 / s1;
            *(float2*)&o[3 * 1048576 + rowoff] = o3;
        }
    }
}

extern "C" void kernel_launch(void* const* d_in, const int* in_sizes, int n_in,
                              void* d_out, int out_size, void* d_ws, size_t ws_size,
                              hipStream_t stream) {
    const void* x   = d_in[0];
    const void* Ind = d_in[1];
    const void* Loc = d_in[2];
    const void* a   = d_in[3];
    const void* W1m = d_in[4];
    const void* b1m = d_in[5];
    const void* W2m = d_in[6];
    const void* b2m = d_in[7];
    const void* W1s = d_in[8];
    const void* b1s = d_in[9];
    const void* W2s = d_in[10];
    const void* b2s = d_in[11];
    const void* E   = d_in[12];
    const void* g   = d_in[13];

    float* ws  = (float*)d_ws;
    float* hAf = ws;                    // [9][64][1024] f32, 2.25 MB
    float* hBf = hAf + 589824;          // [9][64][1024] f32, 2.25 MB
    USH*   Dm  = (USH*)(hBf + 589824);  // [8][1024][1024] bf16, 16 MB

    k_pre_d<<<dim3(2336), 256, 0, stream>>>(x, W1m, b1m, W1s, b1s, E, Ind,
                                            hAf, hBf, Dm);
    k_main<<<dim3(32, 16), 256, 0, stream>>>(hAf, hBf, Dm,
                                             Ind, Loc, a, W2m, b2m, W2s, b2s,
                                             g, d_out);
}